// Round 12
// baseline (170.401 us; speedup 1.0000x reference)
//
#include <hip/hip_runtime.h>
#include <hip/hip_bf16.h>

// ---------------------------------------------------------------------------
// BehaviorSpecificPFF: token-routed 4-expert FFN.
//   y[tok] = relu(x[tok] @ W1[g] + B1[g]) @ W2[g] + B2[g],  g = b_seq[tok]-1
//   b_seq==0 -> zeros.
// Round 12: BIG TILES on the packed layout. Evidence: staging throughput
// pins at ~7.0 TB/s aggregate across r3-r11 (both GEMMs, 416..1664 blocks,
// all sync structures) -> aggregate L2/L3 bandwidth roofline; knob = staged
// bytes. GEMM1: 256x256 (bytes 436->211MB, ~420 blocks). GEMM2: 256x128
// (426->312MB, ~208 blocks). Single-buffer 2-barrier skeleton unchanged
// (dbuf falsified 2x; contiguity falsified r11 but kept - it's free).
// ---------------------------------------------------------------------------

typedef short s16x8 __attribute__((ext_vector_type(8)));
typedef float f32x4 __attribute__((ext_vector_type(4)));

#define NTOK   16384
#define HDIM   512
#define FDIM   2048
#define NEXP   4
#define MAXMT  132   // worst-case total 128-row m-tiles (4 experts)

// ---- header layout (ints) in ws ----
// [0..3] counts  [4..7] cursors  [8..12] token offsets ([12]=total)
// [13..17] gemm1 128-tile bases (pack_a)  [18..22] gemm2 128-tile bases
// [23..27] gemm1 256x256 tile bases ([27]=total)
// [28..32] gemm2 256x128 tile bases ([32]=total)

__global__ void k_init(const int* __restrict__ b_seq,
                       float4* __restrict__ out, int n4) {
  float4 z; z.x = z.y = z.z = z.w = 0.f;
  for (int i = blockIdx.x * blockDim.x + threadIdx.x; i < n4;
       i += gridDim.x * blockDim.x) {
    // non-pad out rows are fully rewritten by GEMM2 every call; only padding
    // rows need zeros (out float4-row token = i>>7).
    if (b_seq[i >> 7] == 0) out[i] = z;
  }
}

__global__ void k_count_scan(const int4* __restrict__ b4,
                             int* __restrict__ hdr) {
  __shared__ int cnt[4];
  if (threadIdx.x < 4) cnt[threadIdx.x] = 0;
  __syncthreads();
  int c0 = 0, c1 = 0, c2 = 0, c3 = 0;
  for (int i = threadIdx.x; i < NTOK / 4; i += 1024) {
    int4 v = b4[i];
    c0 += (v.x == 1) + (v.y == 1) + (v.z == 1) + (v.w == 1);
    c1 += (v.x == 2) + (v.y == 2) + (v.z == 2) + (v.w == 2);
    c2 += (v.x == 3) + (v.y == 3) + (v.z == 3) + (v.w == 3);
    c3 += (v.x == 4) + (v.y == 4) + (v.z == 4) + (v.w == 4);
  }
  if (c0) atomicAdd(&cnt[0], c0);
  if (c1) atomicAdd(&cnt[1], c1);
  if (c2) atomicAdd(&cnt[2], c2);
  if (c3) atomicAdd(&cnt[3], c3);
  __syncthreads();
  if (threadIdx.x == 0) {
    int off = 0, b1 = 0, b2 = 0, q1 = 0, q2 = 0;
    for (int g = 0; g < 4; ++g) {
      int c = cnt[g];
      hdr[g] = c;
      hdr[8 + g] = off;
      hdr[4 + g] = off;   // cursor
      hdr[13 + g] = b1;
      hdr[18 + g] = b2;
      hdr[23 + g] = q1;
      hdr[28 + g] = q2;
      int mt = (c + 127) >> 7;    // 128-row m-tiles
      int mq = (c + 255) >> 8;    // 256-row m-tiles
      off += c;
      b1 += mt * 16;
      b2 += mt * 4;
      q1 += mq * 8;               // GEMM1: 8 n-tiles of 256
      q2 += mq * 4;               // GEMM2: 4 n-tiles of 128
    }
    hdr[12] = off; hdr[17] = b1; hdr[22] = b2; hdr[27] = q1; hdr[32] = q2;
  }
}

// LDS-aggregated fill: one global atomic per (block, expert).
__global__ void k_fill(const int* __restrict__ b_seq, int* __restrict__ hdr,
                       int* __restrict__ perm) {
  __shared__ int lcnt[4], base[4];
  const int tid = threadIdx.x;
  if (tid < 4) lcnt[tid] = 0;
  __syncthreads();
  const int i = blockIdx.x * 256 + tid;
  const int g = b_seq[i];
  int r = -1;
  if (g > 0) r = atomicAdd(&lcnt[g - 1], 1);
  __syncthreads();
  if (tid < 4) {
    int c = lcnt[tid];
    base[tid] = c ? atomicAdd(&hdr[4 + tid], c) : 0;
  }
  __syncthreads();
  if (g > 0) perm[base[g - 1] + r] = i;
}

// Gather + convert x into packed A tiles: xa[mtile][ks(8)][128][64].
// OOB rows of partial tiles are zero-filled.
__global__ __launch_bounds__(256)
void k_pack_a(const float* __restrict__ x, const int* __restrict__ hdr,
              const int* __restrict__ perm, __hip_bfloat16* __restrict__ xa) {
  const int nmt = hdr[17] >> 4;
  const int b = blockIdx.x;
  if (b >= nmt) return;
  int g = 0;
  while ((hdr[13 + g + 1] >> 4) <= b) ++g;
  const int mt = b - (hdr[13 + g] >> 4);
  const int off = hdr[8 + g], cnt = hdr[g];
  int nrows = cnt - (mt << 7);
  nrows = nrows > 128 ? 128 : nrows;
  const int t = threadIdx.x, r = t >> 1, h = t & 1;  // 2 threads/row
  __hip_bfloat16* dstb = xa + ((size_t)b << 16) + (h << 15) + r * 64;
  if (r < nrows) {
    const float* src =
        x + (size_t)perm[off + (mt << 7) + r] * HDIM + (h << 8);
#pragma unroll
    for (int q = 0; q < 4; ++q) {   // ks = h*4 + q
      union { __hip_bfloat16 b16[64]; s16x8 v[8]; } u;
#pragma unroll
      for (int p = 0; p < 16; ++p) {
        float4 vv = *(const float4*)(src + q * 64 + p * 4);
        u.b16[p * 4 + 0] = __float2bfloat16(vv.x);
        u.b16[p * 4 + 1] = __float2bfloat16(vv.y);
        u.b16[p * 4 + 2] = __float2bfloat16(vv.z);
        u.b16[p * 4 + 3] = __float2bfloat16(vv.w);
      }
      s16x8* d = (s16x8*)(dstb + q * 8192);
#pragma unroll
      for (int p = 0; p < 8; ++p) d[p] = u.v[p];
    }
  } else {
    const s16x8 zz = {0, 0, 0, 0, 0, 0, 0, 0};
#pragma unroll
    for (int q = 0; q < 4; ++q) {
      s16x8* d = (s16x8*)(dstb + q * 8192);
#pragma unroll
      for (int p = 0; p < 8; ++p) d[p] = zz;
    }
  }
}

// Transpose+convert W into PACKED K-step tiles:
//   dst tile = (g*(C/128) + (rI/128))*(R/64) + kI/64, elem [rI&127][kI&63]
// grid (C/64, R/64, NEXP), block 256. Stores fully coalesced.
__global__ void k_transpose_cvt(const float* __restrict__ src,
                                __hip_bfloat16* __restrict__ dst, int R, int C) {
  __shared__ float tile[64][69];   // pad 69: conflict-free col reads
  const int g = blockIdx.z;
  const float* S = src + (size_t)g * R * C;
  const int c0 = blockIdx.x << 6, r0 = blockIdx.y << 6;
  const int t = threadIdx.x;
  const int lr = t >> 4, lc = (t & 15) << 2;
#pragma unroll
  for (int p = 0; p < 4; ++p) {
    float4 v = *(const float4*)(S + (size_t)(r0 + lr + p * 16) * C + c0 + lc);
    float* tr = &tile[lr + p * 16][lc];
    tr[0] = v.x; tr[1] = v.y; tr[2] = v.z; tr[3] = v.w;
  }
  __syncthreads();
  const int c = t >> 2, rq = t & 3;
  union { __hip_bfloat16 b[8]; s16x8 v; } u0, u1;
#pragma unroll
  for (int j = 0; j < 8; ++j) {
    u0.b[j] = __float2bfloat16(tile[rq * 16 + j][c]);
    u1.b[j] = __float2bfloat16(tile[rq * 16 + 8 + j][c]);
  }
  const int rI = c0 + c, kI = r0 + rq * 16;
  const size_t idx =
      ((size_t)((g * (C >> 7) + (rI >> 7)) * (R >> 6) + (kI >> 6)) << 13) +
      ((rI & 127) << 6) + (kI & 63);
  *(s16x8*)(dst + idx) = u0.v;
  *(s16x8*)(dst + idx + 8) = u1.v;
}

__device__ __forceinline__ f32x4 mfma16(s16x8 a, s16x8 b, f32x4 c) {
  asm("v_mfma_f32_16x16x32_bf16 %0, %1, %2, %0" : "+v"(c) : "v"(a), "v"(b));
  return c;
}

__device__ __forceinline__ void gload16(const void* g, void* lds) {
  __builtin_amdgcn_global_load_lds(
      (const __attribute__((address_space(1))) unsigned int*)g,
      (__attribute__((address_space(3))) unsigned int*)lds, 16, 0, 0);
}

// Grouped GEMM, BM=256, BK=64, 512 threads = 8 waves (2m x 4n).
// MODE 1: BN=256 (acc[8][4]), A=xa, B=W1p; relu+bias; H out via two
//         128-row LDS half-passes into Hp's packed layout.
// MODE 2: BN=128 (acc[8][2]), A=Hp, B=W2p; +bias; fp32 scatter via perm.
// Operands packed [tile][ks][128][64]; a 256-row/col tile = 2 consecutive
// packed tiles (A clamped at expert boundary; overflow masked at stores).
// Staging: per wave 2 gload16 per 16KB half-tile, each a contiguous 1KB
// block of 8 rows; within-block lane chunk = (l&7)^(row&7) keeps the XOR
// bank swizzle; fragment reads use kb ^ ((row&7)<<4) (r7-r11 proven).
// Skeleton: STAGE -> __syncthreads -> COMPUTE -> __syncthreads.
template <int MODE>
__global__ __launch_bounds__(512, 2)
void k_gemm(const int* __restrict__ hdr, const int* __restrict__ perm,
            const __hip_bfloat16* __restrict__ Ap,
            const __hip_bfloat16* __restrict__ Bp,
            const float* __restrict__ bias,
            __hip_bfloat16* __restrict__ Hout, float* __restrict__ Yout) {
  constexpr int NS   = (MODE == 1) ? 8 : 32;   // K-steps (BK=64)
  constexpr int NT   = (MODE == 1) ? 8 : 4;    // n-tiles per expert
  constexpr int NB   = (MODE == 1) ? 4 : 2;    // 16-col frags per wave
  constexpr int WC   = NB * 16;                // cols per wave (64|32)
  constexpr int NF   = (MODE == 1) ? FDIM : HDIM;
  constexpr int LDSZ = (MODE == 1) ? 65536 : 49152;
  const int* tb = hdr + ((MODE == 1) ? 23 : 28);
  const int total = tb[4];

  __shared__ __align__(16) char LDS[LDSZ];
  char* As = LDS;            // 2 halves x [128][64] = 32KB
  char* Bs = LDS + 32768;    // MODE1: 2 halves (32KB); MODE2: 1 (16KB)

  const int idx = blockIdx.x;
  if (idx >= total) return;
  // m204 runtime-bijective XCD swizzle on the actual tile count
  const int qc = total >> 3, rc = total & 7;
  const int xcd = idx & 7;
  const int cbase = (xcd < rc) ? xcd * (qc + 1) : rc * (qc + 1) + (xcd - rc) * qc;
  const int w = cbase + (idx >> 3);

  const int tid = threadIdx.x, lane = tid & 63, wv = tid >> 6;
  const int wr = wv >> 2, wc = wv & 3;         // wave grid 2m x 4n
  const int l15 = lane & 15, lq = lane >> 4;
  const int rsub = lane >> 3, c8 = lane & 7;   // staging: row-sub, chunk

  int g = 0;
  while (tb[g + 1] <= w) ++g;
  const int local = w - tb[g];
  const int mt = local / NT, nt = local % NT;
  const int cnt = hdr[g], off = hdr[8 + g];
  const int amtBase = hdr[18 + g] >> 2;        // global 128-mtile base
  const int mtcnt = (hdr[18 + g + 1] >> 2) - amtBase;

  // packed-tile indices (A rows: two 128-halves, clamped in-expert)
  const int pA0 = amtBase + (mt << 1);
  const int pA1 = amtBase + ((2 * mt + 1 < mtcnt) ? 2 * mt + 1 : mtcnt - 1);
  const int bt0 = (MODE == 1) ? (g * 16 + (nt << 1)) : (g * 4 + nt);
  const int bt1 = bt0 + 1;                     // used only in MODE 1

  // per-thread source bases (elem offset within an 8KB [128][64] block)
  const int lel = (((wv << 4) + rsub) << 6) + ((c8 ^ rsub) << 3);
  const __hip_bfloat16* aB0 = Ap + (((size_t)pA0 * NS) << 13) + lel;
  const __hip_bfloat16* aB1 = Ap + (((size_t)pA1 * NS) << 13) + lel;
  const __hip_bfloat16* bB0 = Bp + (((size_t)bt0 * NS) << 13) + lel;
  const __hip_bfloat16* bB1 = Bp + (((size_t)bt1 * NS) << 13) + lel;

  f32x4 acc[8][NB];
  const f32x4 fz = {0.f, 0.f, 0.f, 0.f};
#pragma unroll
  for (int m = 0; m < 8; ++m)
#pragma unroll
    for (int n = 0; n < NB; ++n) acc[m][n] = fz;

  const int dwv = wv << 11;                    // wave LDS slice (2KB)
  for (int s = 0; s < NS; ++s) {
    const size_t so = (size_t)s << 13;
    gload16(aB0 + so, As + dwv);
    gload16(aB0 + so + 512, As + dwv + 1024);
    gload16(aB1 + so, As + 16384 + dwv);
    gload16(aB1 + so + 512, As + 16384 + dwv + 1024);
    gload16(bB0 + so, Bs + dwv);
    gload16(bB0 + so + 512, Bs + dwv + 1024);
    if constexpr (MODE == 1) {
      gload16(bB1 + so, Bs + 16384 + dwv);
      gload16(bB1 + so + 512, Bs + 16384 + dwv + 1024);
    }
    __syncthreads();                           // staging visible
#pragma unroll
    for (int kk = 0; kk < 2; ++kk) {
      const int kb = (kk << 6) + (lq << 4);
      s16x8 a[8], b[NB];
#pragma unroll
      for (int m = 0; m < 8; ++m) {
        const int row = (m << 4) + l15;        // within wr half
        a[m] = *(const s16x8*)(As + (wr << 14) + (row << 7) +
                               (kb ^ ((row & 7) << 4)));
      }
#pragma unroll
      for (int n = 0; n < NB; ++n) {
        const int row = wc * WC + (n << 4) + l15;
        b[n] = *(const s16x8*)(Bs + ((row >> 7) << 14) + ((row & 127) << 7) +
                               (kb ^ ((row & 7) << 4)));
      }
#pragma unroll
      for (int m = 0; m < 8; ++m)
#pragma unroll
        for (int n = 0; n < NB; ++n)
          acc[m][n] = mfma16(a[m], b[n], acc[m][n]);
    }
    __syncthreads();                           // reads done before restage
  }
  asm volatile("s_nop 7\ns_nop 7\ns_nop 7");   // MFMA->VALU hazard guard

  const int rq = lq << 2;
  if constexpr (MODE == 1) {
    // two 128-row half-passes: C-stage in LDS [128][256] (512B stride),
    // then 128B stores into Hp packed tiles (amt*32 + nt*4 + q).
#pragma unroll
    for (int h = 0; h < 2; ++h) {
      if (wr == h) {
#pragma unroll
        for (int n = 0; n < 4; ++n) {
          const int col = wc * 64 + (n << 4) + l15;
          const float bv = bias[g * NF + (nt << 8) + col];
#pragma unroll
          for (int m = 0; m < 8; ++m)
#pragma unroll
            for (int j = 0; j < 4; ++j) {
              const int r7 = (m << 4) + rq + j;
              float v = acc[m][n][j] + bv;
              v = v > 0.f ? v : 0.f;
              *(__hip_bfloat16*)(LDS + r7 * 512 + col * 2) =
                  __float2bfloat16(v);
            }
        }
      }
      __syncthreads();
      const int r7 = tid >> 2, q = tid & 3;
      if ((mt << 8) + (h << 7) + r7 < cnt) {
        const size_t tIdx =
            ((size_t)(amtBase + (mt << 1) + h) << 5) + (nt << 2) + q;
        char* dst = (char*)(Hout + (tIdx << 13) + r7 * 64);
        const char* src = LDS + r7 * 512 + q * 128;
#pragma unroll
        for (int p = 0; p < 8; ++p)
          *(s16x8*)(dst + p * 16) = *(const s16x8*)(src + p * 16);
      }
      __syncthreads();
    }
  } else {
#pragma unroll
    for (int n = 0; n < NB; ++n) {
      const int ncol = (nt << 7) + wc * WC + (n << 4) + l15;
      const float bv = bias[g * NF + ncol];
#pragma unroll
      for (int m = 0; m < 8; ++m)
#pragma unroll
        for (int j = 0; j < 4; ++j) {
          const int rl = (wr << 7) + (m << 4) + rq + j;
          if ((mt << 8) + rl < cnt) {
            const int tok = perm[off + (mt << 8) + rl];
            Yout[((size_t)tok << 9) + ncol] = acc[m][n][j] + bv;
          }
        }
    }
  }
}

extern "C" void kernel_launch(void* const* d_in, const int* in_sizes, int n_in,
                              void* d_out, int out_size, void* d_ws,
                              size_t ws_size, hipStream_t stream) {
  const float* x    = (const float*)d_in[0];
  const int* b_seq  = (const int*)d_in[1];
  const float* W1   = (const float*)d_in[2];
  const float* B1   = (const float*)d_in[3];
  const float* W2   = (const float*)d_in[4];
  const float* B2   = (const float*)d_in[5];
  float* out        = (float*)d_out;

  char* ws = (char*)d_ws;
  int* hdr  = (int*)ws;                          // 1 KB header
  int* perm = (int*)(ws + 1024);                 // 64 KB
  __hip_bfloat16* xa  = (__hip_bfloat16*)(ws + 66560);   // 132 mtiles
  __hip_bfloat16* W1p = xa + (size_t)MAXMT * 8 * 8192;   // [4*16][8] tiles
  __hip_bfloat16* W2p = W1p + (size_t)NEXP * FDIM * HDIM;// [4*4][32] tiles
  __hip_bfloat16* Hp  = W2p + (size_t)NEXP * HDIM * FDIM;// 132*32 tiles

  const int n4 = NTOK * HDIM / 4;

  k_init<<<2048, 256, 0, stream>>>(b_seq, (float4*)out, n4);
  k_count_scan<<<1, 1024, 0, stream>>>((const int4*)b_seq, hdr);
  k_fill<<<NTOK / 256, 256, 0, stream>>>(b_seq, hdr, perm);
  k_pack_a<<<MAXMT, 256, 0, stream>>>(x, hdr, perm, xa);
  k_transpose_cvt<<<dim3(FDIM / 64, HDIM / 64, NEXP), 256, 0, stream>>>(
      W1, W1p, HDIM, FDIM);
  k_transpose_cvt<<<dim3(HDIM / 64, FDIM / 64, NEXP), 256, 0, stream>>>(
      W2, W2p, FDIM, HDIM);
  // worst-case tile counts: 68*8=544 (GEMM1), 68*4=272 (GEMM2); early exit
  k_gemm<1><<<544, 512, 0, stream>>>(hdr, perm, xa, W1p, B1, Hp, nullptr);
  k_gemm<2><<<272, 512, 0, stream>>>(hdr, perm, Hp, W2p, B2, nullptr, out);
}

// Round 13
// 155.706 us; speedup vs baseline: 1.0944x; 1.0944x over previous
//
#include <hip/hip_runtime.h>
#include <hip/hip_bf16.h>

// ---------------------------------------------------------------------------
// BehaviorSpecificPFF: token-routed 4-expert FFN.
//   y[tok] = relu(x[tok] @ W1[g] + B1[g]) @ W2[g] + B2[g],  g = b_seq[tok]-1
//   b_seq==0 -> zeros.
// Round 13: COUNTED-VMCNT DEPTH-2 PIPELINE (T4/m248) on r12's exact geometry.
// r12 (single-buffer drain) = depth-0; r8 = depth-1 (issue of s+2 blocked on
// completion of s+1). This round: double buffer + vmcnt(NLD) with NLD = exact
// gloads/thread/K-step (8 GEMM1, 6 GEMM2) -> next-step loads stay in flight
// across both barriers. Everything else (packed operands, staging map,
// fragment reads, epilogues, XCD swizzle) is r12-verbatim (proven correct).
// ---------------------------------------------------------------------------

typedef short s16x8 __attribute__((ext_vector_type(8)));
typedef float f32x4 __attribute__((ext_vector_type(4)));

#define NTOK   16384
#define HDIM   512
#define FDIM   2048
#define NEXP   4
#define MAXMT  132   // worst-case total 128-row m-tiles (4 experts)

// ---- header layout (ints) in ws ----
// [0..3] counts  [4..7] cursors  [8..12] token offsets ([12]=total)
// [13..17] gemm1 128-tile bases (pack_a)  [18..22] gemm2 128-tile bases
// [23..27] gemm1 256x256 tile bases ([27]=total)
// [28..32] gemm2 256x128 tile bases ([32]=total)

__global__ void k_init(const int* __restrict__ b_seq,
                       float4* __restrict__ out, int n4) {
  float4 z; z.x = z.y = z.z = z.w = 0.f;
  for (int i = blockIdx.x * blockDim.x + threadIdx.x; i < n4;
       i += gridDim.x * blockDim.x) {
    // non-pad out rows are fully rewritten by GEMM2 every call; only padding
    // rows need zeros (out float4-row token = i>>7).
    if (b_seq[i >> 7] == 0) out[i] = z;
  }
}

__global__ void k_count_scan(const int4* __restrict__ b4,
                             int* __restrict__ hdr) {
  __shared__ int cnt[4];
  if (threadIdx.x < 4) cnt[threadIdx.x] = 0;
  __syncthreads();
  int c0 = 0, c1 = 0, c2 = 0, c3 = 0;
  for (int i = threadIdx.x; i < NTOK / 4; i += 1024) {
    int4 v = b4[i];
    c0 += (v.x == 1) + (v.y == 1) + (v.z == 1) + (v.w == 1);
    c1 += (v.x == 2) + (v.y == 2) + (v.z == 2) + (v.w == 2);
    c2 += (v.x == 3) + (v.y == 3) + (v.z == 3) + (v.w == 3);
    c3 += (v.x == 4) + (v.y == 4) + (v.z == 4) + (v.w == 4);
  }
  if (c0) atomicAdd(&cnt[0], c0);
  if (c1) atomicAdd(&cnt[1], c1);
  if (c2) atomicAdd(&cnt[2], c2);
  if (c3) atomicAdd(&cnt[3], c3);
  __syncthreads();
  if (threadIdx.x == 0) {
    int off = 0, b1 = 0, b2 = 0, q1 = 0, q2 = 0;
    for (int g = 0; g < 4; ++g) {
      int c = cnt[g];
      hdr[g] = c;
      hdr[8 + g] = off;
      hdr[4 + g] = off;   // cursor
      hdr[13 + g] = b1;
      hdr[18 + g] = b2;
      hdr[23 + g] = q1;
      hdr[28 + g] = q2;
      int mt = (c + 127) >> 7;    // 128-row m-tiles
      int mq = (c + 255) >> 8;    // 256-row m-tiles
      off += c;
      b1 += mt * 16;
      b2 += mt * 4;
      q1 += mq * 8;               // GEMM1: 8 n-tiles of 256
      q2 += mq * 4;               // GEMM2: 4 n-tiles of 128
    }
    hdr[12] = off; hdr[17] = b1; hdr[22] = b2; hdr[27] = q1; hdr[32] = q2;
  }
}

// LDS-aggregated fill: one global atomic per (block, expert).
__global__ void k_fill(const int* __restrict__ b_seq, int* __restrict__ hdr,
                       int* __restrict__ perm) {
  __shared__ int lcnt[4], base[4];
  const int tid = threadIdx.x;
  if (tid < 4) lcnt[tid] = 0;
  __syncthreads();
  const int i = blockIdx.x * 256 + tid;
  const int g = b_seq[i];
  int r = -1;
  if (g > 0) r = atomicAdd(&lcnt[g - 1], 1);
  __syncthreads();
  if (tid < 4) {
    int c = lcnt[tid];
    base[tid] = c ? atomicAdd(&hdr[4 + tid], c) : 0;
  }
  __syncthreads();
  if (g > 0) perm[base[g - 1] + r] = i;
}

// Gather + convert x into packed A tiles: xa[mtile][ks(8)][128][64].
// OOB rows of partial tiles are zero-filled.
__global__ __launch_bounds__(256)
void k_pack_a(const float* __restrict__ x, const int* __restrict__ hdr,
              const int* __restrict__ perm, __hip_bfloat16* __restrict__ xa) {
  const int nmt = hdr[17] >> 4;
  const int b = blockIdx.x;
  if (b >= nmt) return;
  int g = 0;
  while ((hdr[13 + g + 1] >> 4) <= b) ++g;
  const int mt = b - (hdr[13 + g] >> 4);
  const int off = hdr[8 + g], cnt = hdr[g];
  int nrows = cnt - (mt << 7);
  nrows = nrows > 128 ? 128 : nrows;
  const int t = threadIdx.x, r = t >> 1, h = t & 1;  // 2 threads/row
  __hip_bfloat16* dstb = xa + ((size_t)b << 16) + (h << 15) + r * 64;
  if (r < nrows) {
    const float* src =
        x + (size_t)perm[off + (mt << 7) + r] * HDIM + (h << 8);
#pragma unroll
    for (int q = 0; q < 4; ++q) {   // ks = h*4 + q
      union { __hip_bfloat16 b16[64]; s16x8 v[8]; } u;
#pragma unroll
      for (int p = 0; p < 16; ++p) {
        float4 vv = *(const float4*)(src + q * 64 + p * 4);
        u.b16[p * 4 + 0] = __float2bfloat16(vv.x);
        u.b16[p * 4 + 1] = __float2bfloat16(vv.y);
        u.b16[p * 4 + 2] = __float2bfloat16(vv.z);
        u.b16[p * 4 + 3] = __float2bfloat16(vv.w);
      }
      s16x8* d = (s16x8*)(dstb + q * 8192);
#pragma unroll
      for (int p = 0; p < 8; ++p) d[p] = u.v[p];
    }
  } else {
    const s16x8 zz = {0, 0, 0, 0, 0, 0, 0, 0};
#pragma unroll
    for (int q = 0; q < 4; ++q) {
      s16x8* d = (s16x8*)(dstb + q * 8192);
#pragma unroll
      for (int p = 0; p < 8; ++p) d[p] = zz;
    }
  }
}

// Transpose+convert W into PACKED K-step tiles:
//   dst tile = (g*(C/128) + (rI/128))*(R/64) + kI/64, elem [rI&127][kI&63]
// grid (C/64, R/64, NEXP), block 256. Stores fully coalesced.
__global__ void k_transpose_cvt(const float* __restrict__ src,
                                __hip_bfloat16* __restrict__ dst, int R, int C) {
  __shared__ float tile[64][69];   // pad 69: conflict-free col reads
  const int g = blockIdx.z;
  const float* S = src + (size_t)g * R * C;
  const int c0 = blockIdx.x << 6, r0 = blockIdx.y << 6;
  const int t = threadIdx.x;
  const int lr = t >> 4, lc = (t & 15) << 2;
#pragma unroll
  for (int p = 0; p < 4; ++p) {
    float4 v = *(const float4*)(S + (size_t)(r0 + lr + p * 16) * C + c0 + lc);
    float* tr = &tile[lr + p * 16][lc];
    tr[0] = v.x; tr[1] = v.y; tr[2] = v.z; tr[3] = v.w;
  }
  __syncthreads();
  const int c = t >> 2, rq = t & 3;
  union { __hip_bfloat16 b[8]; s16x8 v; } u0, u1;
#pragma unroll
  for (int j = 0; j < 8; ++j) {
    u0.b[j] = __float2bfloat16(tile[rq * 16 + j][c]);
    u1.b[j] = __float2bfloat16(tile[rq * 16 + 8 + j][c]);
  }
  const int rI = c0 + c, kI = r0 + rq * 16;
  const size_t idx =
      ((size_t)((g * (C >> 7) + (rI >> 7)) * (R >> 6) + (kI >> 6)) << 13) +
      ((rI & 127) << 6) + (kI & 63);
  *(s16x8*)(dst + idx) = u0.v;
  *(s16x8*)(dst + idx + 8) = u1.v;
}

__device__ __forceinline__ f32x4 mfma16(s16x8 a, s16x8 b, f32x4 c) {
  asm("v_mfma_f32_16x16x32_bf16 %0, %1, %2, %0" : "+v"(c) : "v"(a), "v"(b));
  return c;
}

__device__ __forceinline__ void gload16(const void* g, void* lds) {
  __builtin_amdgcn_global_load_lds(
      (const __attribute__((address_space(1))) unsigned int*)g,
      (__attribute__((address_space(3))) unsigned int*)lds, 16, 0, 0);
}

// Grouped GEMM, BM=256, BK=64, 512 threads = 8 waves (2m x 4n).
// MODE 1: BN=256 (acc[8][4]), A=xa, B=W1p; relu+bias; Hp epilogue.
// MODE 2: BN=128 (acc[8][2]), A=Hp, B=W2p; +bias; fp32 scatter via perm.
// K-loop: double-buffered counted pipeline --
//   STAGE(0->buf0); for s: { STAGE(s+1 -> p^1); vmcnt(NLD); barrier;
//                            COMPUTE(p); barrier; }
// NLD = gloads/thread/step (8|6). At the wait, outstanding = 2*NLD, so
// vmcnt(NLD) retires exactly the step-s batch; step-s+1 loads remain in
// flight across both barriers (depth-2 MLP). No other vmem in loop body.
// End-of-iter barrier separates COMPUTE(p) reads from next STAGE into p.
template <int MODE>
__global__ __launch_bounds__(512, 2)
void k_gemm(const int* __restrict__ hdr, const int* __restrict__ perm,
            const __hip_bfloat16* __restrict__ Ap,
            const __hip_bfloat16* __restrict__ Bp,
            const float* __restrict__ bias,
            __hip_bfloat16* __restrict__ Hout, float* __restrict__ Yout) {
  constexpr int NS   = (MODE == 1) ? 8 : 32;   // K-steps (BK=64)
  constexpr int NT   = (MODE == 1) ? 8 : 4;    // n-tiles per expert
  constexpr int NB   = (MODE == 1) ? 4 : 2;    // 16-col frags per wave
  constexpr int WC   = NB * 16;                // cols per wave (64|32)
  constexpr int NF   = (MODE == 1) ? FDIM : HDIM;
  constexpr int ABUFSZ = 32768;                // 2 halves x [128][64]
  constexpr int BBUFSZ = (MODE == 1) ? 32768 : 16384;
  constexpr int LDSZ = 2 * ABUFSZ + 2 * BBUFSZ;   // 128KB | 96KB
  const int* tb = hdr + ((MODE == 1) ? 23 : 28);
  const int total = tb[4];

  __shared__ __align__(16) char LDS[LDSZ];
  char* As = LDS;                 // + p*ABUFSZ
  char* Bs = LDS + 2 * ABUFSZ;    // + p*BBUFSZ

  const int idx = blockIdx.x;
  if (idx >= total) return;
  // m204 runtime-bijective XCD swizzle on the actual tile count
  const int qc = total >> 3, rc = total & 7;
  const int xcd = idx & 7;
  const int cbase = (xcd < rc) ? xcd * (qc + 1) : rc * (qc + 1) + (xcd - rc) * qc;
  const int w = cbase + (idx >> 3);

  const int tid = threadIdx.x, lane = tid & 63, wv = tid >> 6;
  const int wr = wv >> 2, wc = wv & 3;         // wave grid 2m x 4n
  const int l15 = lane & 15, lq = lane >> 4;
  const int rsub = lane >> 3, c8 = lane & 7;   // staging: row-sub, chunk

  int g = 0;
  while (tb[g + 1] <= w) ++g;
  const int local = w - tb[g];
  const int mt = local / NT, nt = local % NT;
  const int cnt = hdr[g], off = hdr[8 + g];
  const int amtBase = hdr[18 + g] >> 2;        // global 128-mtile base
  const int mtcnt = (hdr[18 + g + 1] >> 2) - amtBase;

  // packed-tile indices (A rows: two 128-halves, clamped in-expert)
  const int pA0 = amtBase + (mt << 1);
  const int pA1 = amtBase + ((2 * mt + 1 < mtcnt) ? 2 * mt + 1 : mtcnt - 1);
  const int bt0 = (MODE == 1) ? (g * 16 + (nt << 1)) : (g * 4 + nt);
  const int bt1 = bt0 + 1;                     // used only in MODE 1

  // per-thread source bases (elem offset within an 8KB [128][64] block)
  const int lel = (((wv << 4) + rsub) << 6) + ((c8 ^ rsub) << 3);
  const __hip_bfloat16* aB0 = Ap + (((size_t)pA0 * NS) << 13) + lel;
  const __hip_bfloat16* aB1 = Ap + (((size_t)pA1 * NS) << 13) + lel;
  const __hip_bfloat16* bB0 = Bp + (((size_t)bt0 * NS) << 13) + lel;
  const __hip_bfloat16* bB1 = Bp + (((size_t)bt1 * NS) << 13) + lel;

  f32x4 acc[8][NB];
  const f32x4 fz = {0.f, 0.f, 0.f, 0.f};
#pragma unroll
  for (int m = 0; m < 8; ++m)
#pragma unroll
    for (int n = 0; n < NB; ++n) acc[m][n] = fz;

  const int dwv = wv << 11;                    // wave LDS slice (2KB)

  auto STAGE = [&](int s, int p) {
    const size_t so = (size_t)s << 13;
    char* Ad = As + p * ABUFSZ + dwv;
    char* Bd = Bs + p * BBUFSZ + dwv;
    gload16(aB0 + so, Ad);
    gload16(aB0 + so + 512, Ad + 1024);
    gload16(aB1 + so, Ad + 16384);
    gload16(aB1 + so + 512, Ad + 16384 + 1024);
    gload16(bB0 + so, Bd);
    gload16(bB0 + so + 512, Bd + 1024);
    if constexpr (MODE == 1) {
      gload16(bB1 + so, Bd + 16384);
      gload16(bB1 + so + 512, Bd + 16384 + 1024);
    }
  };
  auto COMPUTE = [&](int p) {
    const char* Ab = As + p * ABUFSZ;
    const char* Bb = Bs + p * BBUFSZ;
#pragma unroll
    for (int kk = 0; kk < 2; ++kk) {
      const int kb = (kk << 6) + (lq << 4);
      s16x8 a[8], b[NB];
#pragma unroll
      for (int m = 0; m < 8; ++m) {
        const int row = (m << 4) + l15;        // within wr half
        a[m] = *(const s16x8*)(Ab + (wr << 14) + (row << 7) +
                               (kb ^ ((row & 7) << 4)));
      }
#pragma unroll
      for (int n = 0; n < NB; ++n) {
        const int row = wc * WC + (n << 4) + l15;
        b[n] = *(const s16x8*)(Bb + ((row >> 7) << 14) + ((row & 127) << 7) +
                               (kb ^ ((row & 7) << 4)));
      }
#pragma unroll
      for (int m = 0; m < 8; ++m)
#pragma unroll
        for (int n = 0; n < NB; ++n)
          acc[m][n] = mfma16(a[m], b[n], acc[m][n]);
    }
  };

  // counted depth-2 pipeline
  STAGE(0, 0);
  for (int s = 0; s < NS; ++s) {
    const int p = s & 1;
    if (s + 1 < NS) {
      STAGE(s + 1, p ^ 1);
      if constexpr (MODE == 1)
        asm volatile("s_waitcnt vmcnt(8)" ::: "memory");
      else
        asm volatile("s_waitcnt vmcnt(6)" ::: "memory");
    } else {
      asm volatile("s_waitcnt vmcnt(0)" ::: "memory");
    }
    __builtin_amdgcn_s_barrier();              // step-s data visible to all
    asm volatile("" ::: "memory");
    COMPUTE(p);
    asm volatile("" ::: "memory");
    __builtin_amdgcn_s_barrier();              // reads of p done before
    asm volatile("" ::: "memory");             // next STAGE overwrites p
  }
  asm volatile("s_nop 7\ns_nop 7\ns_nop 7");   // MFMA->VALU hazard guard

  const int rq = lq << 2;
  if constexpr (MODE == 1) {
    // two 128-row half-passes: C-stage in LDS [128][256] (512B stride),
    // then 128B stores into Hp packed tiles (amt*32 + nt*4 + q).
#pragma unroll
    for (int h = 0; h < 2; ++h) {
      if (wr == h) {
#pragma unroll
        for (int n = 0; n < 4; ++n) {
          const int col = wc * 64 + (n << 4) + l15;
          const float bv = bias[g * NF + (nt << 8) + col];
#pragma unroll
          for (int m = 0; m < 8; ++m)
#pragma unroll
            for (int j = 0; j < 4; ++j) {
              const int r7 = (m << 4) + rq + j;
              float v = acc[m][n][j] + bv;
              v = v > 0.f ? v : 0.f;
              *(__hip_bfloat16*)(LDS + r7 * 512 + col * 2) =
                  __float2bfloat16(v);
            }
        }
      }
      __syncthreads();
      const int r7 = tid >> 2, q = tid & 3;
      if ((mt << 8) + (h << 7) + r7 < cnt) {
        const size_t tIdx =
            ((size_t)(amtBase + (mt << 1) + h) << 5) + (nt << 2) + q;
        char* dst = (char*)(Hout + (tIdx << 13) + r7 * 64);
        const char* src = LDS + r7 * 512 + q * 128;
#pragma unroll
        for (int p2 = 0; p2 < 8; ++p2)
          *(s16x8*)(dst + p2 * 16) = *(const s16x8*)(src + p2 * 16);
      }
      __syncthreads();
    }
  } else {
#pragma unroll
    for (int n = 0; n < NB; ++n) {
      const int ncol = (nt << 7) + wc * WC + (n << 4) + l15;
      const float bv = bias[g * NF + ncol];
#pragma unroll
      for (int m = 0; m < 8; ++m)
#pragma unroll
        for (int j = 0; j < 4; ++j) {
          const int rl = (wr << 7) + (m << 4) + rq + j;
          if ((mt << 8) + rl < cnt) {
            const int tok = perm[off + (mt << 8) + rl];
            Yout[((size_t)tok << 9) + ncol] = acc[m][n][j] + bv;
          }
        }
    }
  }
}

extern "C" void kernel_launch(void* const* d_in, const int* in_sizes, int n_in,
                              void* d_out, int out_size, void* d_ws,
                              size_t ws_size, hipStream_t stream) {
  const float* x    = (const float*)d_in[0];
  const int* b_seq  = (const int*)d_in[1];
  const float* W1   = (const float*)d_in[2];
  const float* B1   = (const float*)d_in[3];
  const float* W2   = (const float*)d_in[4];
  const float* B2   = (const float*)d_in[5];
  float* out        = (float*)d_out;

  char* ws = (char*)d_ws;
  int* hdr  = (int*)ws;                          // 1 KB header
  int* perm = (int*)(ws + 1024);                 // 64 KB
  __hip_bfloat16* xa  = (__hip_bfloat16*)(ws + 66560);   // 132 mtiles
  __hip_bfloat16* W1p = xa + (size_t)MAXMT * 8 * 8192;   // [4*16][8] tiles
  __hip_bfloat16* W2p = W1p + (size_t)NEXP * FDIM * HDIM;// [4*4][32] tiles
  __hip_bfloat16* Hp  = W2p + (size_t)NEXP * HDIM * FDIM;// 132*32 tiles

  const int n4 = NTOK * HDIM / 4;

  k_init<<<2048, 256, 0, stream>>>(b_seq, (float4*)out, n4);
  k_count_scan<<<1, 1024, 0, stream>>>((const int4*)b_seq, hdr);
  k_fill<<<NTOK / 256, 256, 0, stream>>>(b_seq, hdr, perm);
  k_pack_a<<<MAXMT, 256, 0, stream>>>(x, hdr, perm, xa);
  k_transpose_cvt<<<dim3(FDIM / 64, HDIM / 64, NEXP), 256, 0, stream>>>(
      W1, W1p, HDIM, FDIM);
  k_transpose_cvt<<<dim3(HDIM / 64, FDIM / 64, NEXP), 256, 0, stream>>>(
      W2, W2p, FDIM, HDIM);
  // worst-case tile counts: 68*8=544 (GEMM1), 68*4=272 (GEMM2); early exit
  k_gemm<1><<<544, 512, 0, stream>>>(hdr, perm, xa, W1p, B1, Hp, nullptr);
  k_gemm<2><<<272, 512, 0, stream>>>(hdr, perm, Hp, W2p, B2, nullptr, out);
}

// Round 14
// 144.044 us; speedup vs baseline: 1.1830x; 1.0810x over previous
//
#include <hip/hip_runtime.h>
#include <hip/hip_bf16.h>

// ---------------------------------------------------------------------------
// BehaviorSpecificPFF: token-routed 4-expert FFN.
//   y[tok] = relu(x[tok] @ W1[g] + B1[g]) @ W2[g] + B2[g],  g = b_seq[tok]-1
//   b_seq==0 -> zeros.
// Round 14: r11 geometry (128x128 tile, BK=64, 256 thr, packed operands,
// proven epilogues) + r13-proven counted depth-2 pipeline (T4): double
// buffer, STAGE(s+1) -> vmcnt(8) -> barrier -> COMPUTE(p) -> barrier.
// LDS 64KB -> 2 blocks/CU residency on top of the pipeline (r13's 256-geom
// paid 1 block/CU + 2-round tail; this geometry avoids both).
// ---------------------------------------------------------------------------

typedef short s16x8 __attribute__((ext_vector_type(8)));
typedef float f32x4 __attribute__((ext_vector_type(4)));

#define NTOK   16384
#define HDIM   512
#define FDIM   2048
#define NEXP   4
#define MAXMT  132   // worst-case total 128-row m-tiles (4 experts)

// ---- header layout (ints) in ws ----
// [0..3] counts  [4..7] cursors  [8..12] token offsets ([12]=total)
// [13..17] gemm1 tile bases, mt-base = hdr[13+g]>>4 ([17]=total)
// [18..22] gemm2 tile bases, mt-base = hdr[18+g]>>2

__global__ void k_init(const int* __restrict__ b_seq,
                       float4* __restrict__ out, int n4) {
  float4 z; z.x = z.y = z.z = z.w = 0.f;
  for (int i = blockIdx.x * blockDim.x + threadIdx.x; i < n4;
       i += gridDim.x * blockDim.x) {
    // non-pad out rows are fully rewritten by GEMM2 every call; only padding
    // rows need zeros (out float4-row token = i>>7).
    if (b_seq[i >> 7] == 0) out[i] = z;
  }
}

__global__ void k_count_scan(const int4* __restrict__ b4,
                             int* __restrict__ hdr) {
  __shared__ int cnt[4];
  if (threadIdx.x < 4) cnt[threadIdx.x] = 0;
  __syncthreads();
  int c0 = 0, c1 = 0, c2 = 0, c3 = 0;
  for (int i = threadIdx.x; i < NTOK / 4; i += 1024) {
    int4 v = b4[i];
    c0 += (v.x == 1) + (v.y == 1) + (v.z == 1) + (v.w == 1);
    c1 += (v.x == 2) + (v.y == 2) + (v.z == 2) + (v.w == 2);
    c2 += (v.x == 3) + (v.y == 3) + (v.z == 3) + (v.w == 3);
    c3 += (v.x == 4) + (v.y == 4) + (v.z == 4) + (v.w == 4);
  }
  if (c0) atomicAdd(&cnt[0], c0);
  if (c1) atomicAdd(&cnt[1], c1);
  if (c2) atomicAdd(&cnt[2], c2);
  if (c3) atomicAdd(&cnt[3], c3);
  __syncthreads();
  if (threadIdx.x == 0) {
    int off = 0, b1 = 0, b2 = 0;
    for (int g = 0; g < 4; ++g) {
      int c = cnt[g];
      hdr[g] = c;
      hdr[8 + g] = off;
      hdr[4 + g] = off;   // cursor
      hdr[13 + g] = b1;
      hdr[18 + g] = b2;
      int mt = (c + 127) >> 7;   // 128-row m-tiles
      off += c;
      b1 += mt * 16;
      b2 += mt * 4;
    }
    hdr[12] = off; hdr[17] = b1; hdr[22] = b2;
  }
}

// LDS-aggregated fill: one global atomic per (block, expert).
__global__ void k_fill(const int* __restrict__ b_seq, int* __restrict__ hdr,
                       int* __restrict__ perm) {
  __shared__ int lcnt[4], base[4];
  const int tid = threadIdx.x;
  if (tid < 4) lcnt[tid] = 0;
  __syncthreads();
  const int i = blockIdx.x * 256 + tid;
  const int g = b_seq[i];
  int r = -1;
  if (g > 0) r = atomicAdd(&lcnt[g - 1], 1);
  __syncthreads();
  if (tid < 4) {
    int c = lcnt[tid];
    base[tid] = c ? atomicAdd(&hdr[4 + tid], c) : 0;
  }
  __syncthreads();
  if (g > 0) perm[base[g - 1] + r] = i;
}

// Gather + convert x into packed A tiles: xa[mtile][ks(8)][128][64].
// OOB rows of partial tiles are zero-filled.
__global__ __launch_bounds__(256)
void k_pack_a(const float* __restrict__ x, const int* __restrict__ hdr,
              const int* __restrict__ perm, __hip_bfloat16* __restrict__ xa) {
  const int nmt = hdr[17] >> 4;
  const int b = blockIdx.x;
  if (b >= nmt) return;
  int g = 0;
  while ((hdr[13 + g + 1] >> 4) <= b) ++g;
  const int mt = b - (hdr[13 + g] >> 4);
  const int off = hdr[8 + g], cnt = hdr[g];
  int nrows = cnt - (mt << 7);
  nrows = nrows > 128 ? 128 : nrows;
  const int t = threadIdx.x, r = t >> 1, h = t & 1;  // 2 threads/row
  __hip_bfloat16* dstb = xa + ((size_t)b << 16) + (h << 15) + r * 64;
  if (r < nrows) {
    const float* src =
        x + (size_t)perm[off + (mt << 7) + r] * HDIM + (h << 8);
#pragma unroll
    for (int q = 0; q < 4; ++q) {   // ks = h*4 + q
      union { __hip_bfloat16 b16[64]; s16x8 v[8]; } u;
#pragma unroll
      for (int p = 0; p < 16; ++p) {
        float4 vv = *(const float4*)(src + q * 64 + p * 4);
        u.b16[p * 4 + 0] = __float2bfloat16(vv.x);
        u.b16[p * 4 + 1] = __float2bfloat16(vv.y);
        u.b16[p * 4 + 2] = __float2bfloat16(vv.z);
        u.b16[p * 4 + 3] = __float2bfloat16(vv.w);
      }
      s16x8* d = (s16x8*)(dstb + q * 8192);
#pragma unroll
      for (int p = 0; p < 8; ++p) d[p] = u.v[p];
    }
  } else {
    const s16x8 zz = {0, 0, 0, 0, 0, 0, 0, 0};
#pragma unroll
    for (int q = 0; q < 4; ++q) {
      s16x8* d = (s16x8*)(dstb + q * 8192);
#pragma unroll
      for (int p = 0; p < 8; ++p) d[p] = zz;
    }
  }
}

// Transpose+convert W into PACKED K-step tiles:
//   dst tile = (g*(C/128) + (rI/128))*(R/64) + kI/64, elem [rI&127][kI&63]
// grid (C/64, R/64, NEXP), block 256. Stores fully coalesced.
__global__ void k_transpose_cvt(const float* __restrict__ src,
                                __hip_bfloat16* __restrict__ dst, int R, int C) {
  __shared__ float tile[64][69];   // pad 69: conflict-free col reads
  const int g = blockIdx.z;
  const float* S = src + (size_t)g * R * C;
  const int c0 = blockIdx.x << 6, r0 = blockIdx.y << 6;
  const int t = threadIdx.x;
  const int lr = t >> 4, lc = (t & 15) << 2;
#pragma unroll
  for (int p = 0; p < 4; ++p) {
    float4 v = *(const float4*)(S + (size_t)(r0 + lr + p * 16) * C + c0 + lc);
    float* tr = &tile[lr + p * 16][lc];
    tr[0] = v.x; tr[1] = v.y; tr[2] = v.z; tr[3] = v.w;
  }
  __syncthreads();
  const int c = t >> 2, rq = t & 3;
  union { __hip_bfloat16 b[8]; s16x8 v; } u0, u1;
#pragma unroll
  for (int j = 0; j < 8; ++j) {
    u0.b[j] = __float2bfloat16(tile[rq * 16 + j][c]);
    u1.b[j] = __float2bfloat16(tile[rq * 16 + 8 + j][c]);
  }
  const int rI = c0 + c, kI = r0 + rq * 16;
  const size_t idx =
      ((size_t)((g * (C >> 7) + (rI >> 7)) * (R >> 6) + (kI >> 6)) << 13) +
      ((rI & 127) << 6) + (kI & 63);
  *(s16x8*)(dst + idx) = u0.v;
  *(s16x8*)(dst + idx + 8) = u1.v;
}

__device__ __forceinline__ f32x4 mfma16(s16x8 a, s16x8 b, f32x4 c) {
  asm("v_mfma_f32_16x16x32_bf16 %0, %1, %2, %0" : "+v"(c) : "v"(a), "v"(b));
  return c;
}

__device__ __forceinline__ void gload16(const void* g, void* lds) {
  __builtin_amdgcn_global_load_lds(
      (const __attribute__((address_space(1))) unsigned int*)g,
      (__attribute__((address_space(3))) unsigned int*)lds, 16, 0, 0);
}

// Grouped GEMM, 128x128 tile, BK=64, 4 waves each computing [64,64].
// Operands packed [tile][ks][128][64]: each wave-instruction stages a
// contiguous 1KB block; lane chunk (l&7)^(row&7) keeps the XOR bank swizzle
// inside the block; fragment reads use kb ^ ((row&7)<<4) (r7-r13 proven).
// K-loop (T4, r13-proven): double buffer + counted vmcnt --
//   STAGE(0,0); for s: { STAGE(s+1,p^1); vmcnt(8); barrier;
//                        COMPUTE(p); barrier; }
// NLD=8 = gloads/thread/step (4 A + 4 B); at the wait outstanding=16, so
// vmcnt(8) retires exactly step-s's batch; step-s+1 loads stay in flight
// across both barriers. No other vmem in the loop body.
// MODE 1: A = xa (K=512), B = W1p; relu+bias; C staged in LDS (stride 272)
//         then 128B stores into Hp in GEMM2's packed-tile layout.
// MODE 2: A = Hp (K=2048), B = W2p; +bias; fp32 scatter to d_out via perm.
template <int MODE>
__global__ __launch_bounds__(256, 2)
void k_gemm(const int* __restrict__ hdr, const int* __restrict__ perm,
            const __hip_bfloat16* __restrict__ Ap,
            const __hip_bfloat16* __restrict__ Bp,
            const float* __restrict__ bias,
            __hip_bfloat16* __restrict__ Hout, float* __restrict__ Yout) {
  constexpr int NS   = (MODE == 1) ? 8 : 32;   // K-steps
  constexpr int NT   = (MODE == 1) ? 16 : 4;   // n-tiles
  constexpr int NF   = (MODE == 1) ? FDIM : HDIM;
  const int* tb = hdr + ((MODE == 1) ? 13 : 18);
  const int total = tb[4];

  __shared__ __align__(16) char LDS[65536];
  char* As = LDS;            // + p*16384
  char* Bs = LDS + 32768;    // + p*16384

  const int idx = blockIdx.x;
  if (idx >= total) return;
  // m204 runtime-bijective XCD swizzle on the actual tile count
  const int qc = total >> 3, rc = total & 7;
  const int xcd = idx & 7;
  const int cbase = (xcd < rc) ? xcd * (qc + 1) : rc * (qc + 1) + (xcd - rc) * qc;
  const int w = cbase + (idx >> 3);

  const int tid = threadIdx.x, lane = tid & 63, wv = tid >> 6;
  const int wm = (wv >> 1) << 6, wn = (wv & 1) << 6;
  const int l15 = lane & 15, lq = lane >> 4;
  const int rsub = lane >> 3, c8 = lane & 7;      // staging: row-sub, chunk

  int g = 0;
  while (tb[g + 1] <= w) ++g;
  const int local = w - tb[g];
  const int mt = local / NT, nt = local % NT;
  const int cnt = hdr[g], off = hdr[8 + g];
  int nrows = cnt - (mt << 7);
  nrows = nrows > 128 ? 128 : nrows;

  // packed-tile sequence bases; K-step s adds s*8192 elements
  const int amt = (MODE == 1) ? (hdr[13 + g] >> 4) + mt
                              : (hdr[18 + g] >> 2) + mt;
  const int lelem = ((wv << 5) + rsub) * 64 + ((c8 ^ rsub) << 3);
  const __hip_bfloat16* abase = Ap + (((size_t)amt * NS) << 13) + lelem;
  const __hip_bfloat16* bbase =
      Bp + (((size_t)(g * NT + nt) * NS) << 13) + lelem;

  f32x4 acc[4][4];
  const f32x4 fz = {0.f, 0.f, 0.f, 0.f};
#pragma unroll
  for (int m = 0; m < 4; ++m)
#pragma unroll
    for (int n = 0; n < 4; ++n) acc[m][n] = fz;

  auto STAGE = [&](int s, int p) {
    const size_t so = (size_t)s << 13;
    char* Ad = As + (p << 14) + (wv << 12);
    char* Bd = Bs + (p << 14) + (wv << 12);
#pragma unroll
    for (int i = 0; i < 4; ++i) {
      gload16(abase + so + (i << 9), Ad + (i << 10));
      gload16(bbase + so + (i << 9), Bd + (i << 10));
    }
  };
  auto COMPUTE = [&](int p) {
    const char* Ab = As + (p << 14);
    const char* Bb = Bs + (p << 14);
#pragma unroll
    for (int kk = 0; kk < 2; ++kk) {
      const int kb = (kk << 6) + (lq << 4);
      s16x8 a[4], b[4];
#pragma unroll
      for (int m = 0; m < 4; ++m) {
        const int row = wm + (m << 4) + l15;
        a[m] = *(const s16x8*)(Ab + (row << 7) + (kb ^ ((row & 7) << 4)));
      }
#pragma unroll
      for (int n = 0; n < 4; ++n) {
        const int row = wn + (n << 4) + l15;
        b[n] = *(const s16x8*)(Bb + (row << 7) + (kb ^ ((row & 7) << 4)));
      }
#pragma unroll
      for (int m = 0; m < 4; ++m)
#pragma unroll
        for (int n = 0; n < 4; ++n)
          acc[m][n] = mfma16(a[m], b[n], acc[m][n]);
    }
  };

  // counted depth-2 pipeline (T4)
  STAGE(0, 0);
  for (int s = 0; s < NS; ++s) {
    const int p = s & 1;
    if (s + 1 < NS) {
      STAGE(s + 1, p ^ 1);
      asm volatile("s_waitcnt vmcnt(8)" ::: "memory");  // step-s retired
    } else {
      asm volatile("s_waitcnt vmcnt(0)" ::: "memory");
    }
    __builtin_amdgcn_s_barrier();              // step-s data visible to all
    asm volatile("" ::: "memory");
    COMPUTE(p);
    asm volatile("" ::: "memory");
    __builtin_amdgcn_s_barrier();              // reads of p done before
    asm volatile("" ::: "memory");             // next STAGE overwrites p
  }
  asm volatile("s_nop 7\ns_nop 7\ns_nop 7");   // MFMA->VALU hazard guard

  const int rq = lq << 2;
  if constexpr (MODE == 1) {
    // stage relu(acc+bias) in LDS (stride 272), then 128B stores into Hp's
    // packed layout: tile (amt2*32 + nt*2 + hf), elem [r][f&63].
#pragma unroll
    for (int n = 0; n < 4; ++n) {
      const int col = wn + (n << 4) + l15;
      const float bv = bias[g * NF + (nt << 7) + col];
#pragma unroll
      for (int m = 0; m < 4; ++m)
#pragma unroll
        for (int j = 0; j < 4; ++j) {
          const int row = wm + (m << 4) + rq + j;
          float v = acc[m][n][j] + bv;
          v = v > 0.f ? v : 0.f;
          *(__hip_bfloat16*)(LDS + row * 272 + col * 2) = __float2bfloat16(v);
        }
    }
    __syncthreads();
    const int r = tid >> 1, hf = tid & 1;
    if (r < nrows) {
      const char* src = LDS + r * 272 + hf * 128;
      const size_t tIdx =
          ((size_t)((hdr[18 + g] >> 2) + mt) * 32 + (nt << 1) + hf);
      char* dst = (char*)(Hout + (tIdx << 13) + r * 64);
#pragma unroll
      for (int q = 0; q < 8; ++q)
        *(s16x8*)(dst + q * 16) = *(const s16x8*)(src + q * 16);
    }
  } else {
#pragma unroll
    for (int n = 0; n < 4; ++n) {
      const int ncol = (nt << 7) + wn + (n << 4) + l15;
      const float bv = bias[g * NF + ncol];
#pragma unroll
      for (int m = 0; m < 4; ++m)
#pragma unroll
        for (int j = 0; j < 4; ++j) {
          const int rl = wm + (m << 4) + rq + j;
          if (rl < nrows) {
            const int tok = perm[off + (mt << 7) + rl];
            Yout[((size_t)tok << 9) + ncol] = acc[m][n][j] + bv;
          }
        }
    }
  }
}

extern "C" void kernel_launch(void* const* d_in, const int* in_sizes, int n_in,
                              void* d_out, int out_size, void* d_ws,
                              size_t ws_size, hipStream_t stream) {
  const float* x    = (const float*)d_in[0];
  const int* b_seq  = (const int*)d_in[1];
  const float* W1   = (const float*)d_in[2];
  const float* B1   = (const float*)d_in[3];
  const float* W2   = (const float*)d_in[4];
  const float* B2   = (const float*)d_in[5];
  float* out        = (float*)d_out;

  char* ws = (char*)d_ws;
  int* hdr  = (int*)ws;                          // 1 KB header
  int* perm = (int*)(ws + 1024);                 // 64 KB
  __hip_bfloat16* xa  = (__hip_bfloat16*)(ws + 66560);   // 132 mtiles
  __hip_bfloat16* W1p = xa + (size_t)MAXMT * 8 * 8192;   // [4*16][8] tiles
  __hip_bfloat16* W2p = W1p + (size_t)NEXP * FDIM * HDIM;// [4*4][32] tiles
  __hip_bfloat16* Hp  = W2p + (size_t)NEXP * HDIM * FDIM;// 132*32 tiles

  const int n4 = NTOK * HDIM / 4;

  k_init<<<2048, 256, 0, stream>>>(b_seq, (float4*)out, n4);
  k_count_scan<<<1, 1024, 0, stream>>>((const int4*)b_seq, hdr);
  k_fill<<<NTOK / 256, 256, 0, stream>>>(b_seq, hdr, perm);
  k_pack_a<<<MAXMT, 256, 0, stream>>>(x, hdr, perm, xa);
  k_transpose_cvt<<<dim3(FDIM / 64, HDIM / 64, NEXP), 256, 0, stream>>>(
      W1, W1p, HDIM, FDIM);
  k_transpose_cvt<<<dim3(HDIM / 64, FDIM / 64, NEXP), 256, 0, stream>>>(
      W2, W2p, FDIM, HDIM);
  // grids cover worst-case tile counts; blocks past the actual total exit
  k_gemm<1><<<2112, 256, 0, stream>>>(hdr, perm, xa, W1p, B1, Hp, nullptr);
  k_gemm<2><<<528, 256, 0, stream>>>(hdr, perm, Hp, W2p, B2, nullptr, out);
}

// Round 15
// 140.444 us; speedup vs baseline: 1.2133x; 1.0256x over previous
//
#include <hip/hip_runtime.h>
#include <hip/hip_bf16.h>

// ---------------------------------------------------------------------------
// BehaviorSpecificPFF: token-routed 4-expert FFN.
//   y[tok] = relu(x[tok] @ W1[g] + B1[g]) @ W2[g] + B2[g],  g = b_seq[tok]-1
//   b_seq==0 -> zeros.
// Round 15: r14 GEMM (T4 counted depth-2, 128^2, packed operands) +
//  (a) k_pack_a parallelism x8 (grid nmt*8, one block per (mtile,ks)) --
//      r11-r14's ~18us prep overhead was the 104-block gather kernel;
//  (b) T5 s_setprio(1) around the MFMA cluster -- null on lockstep (m190)
//      but +21-39% on counted-vmcnt schedules (m218b); r14 is that class.
// ---------------------------------------------------------------------------

typedef short s16x8 __attribute__((ext_vector_type(8)));
typedef float f32x4 __attribute__((ext_vector_type(4)));

#define NTOK   16384
#define HDIM   512
#define FDIM   2048
#define NEXP   4
#define MAXMT  132   // worst-case total 128-row m-tiles (4 experts)

// ---- header layout (ints) in ws ----
// [0..3] counts  [4..7] cursors  [8..12] token offsets ([12]=total)
// [13..17] gemm1 tile bases, mt-base = hdr[13+g]>>4 ([17]=total)
// [18..22] gemm2 tile bases, mt-base = hdr[18+g]>>2

__global__ void k_init(const int* __restrict__ b_seq,
                       float4* __restrict__ out, int n4) {
  float4 z; z.x = z.y = z.z = z.w = 0.f;
  for (int i = blockIdx.x * blockDim.x + threadIdx.x; i < n4;
       i += gridDim.x * blockDim.x) {
    // non-pad out rows are fully rewritten by GEMM2 every call; only padding
    // rows need zeros (out float4-row token = i>>7).
    if (b_seq[i >> 7] == 0) out[i] = z;
  }
}

__global__ void k_count_scan(const int4* __restrict__ b4,
                             int* __restrict__ hdr) {
  __shared__ int cnt[4];
  if (threadIdx.x < 4) cnt[threadIdx.x] = 0;
  __syncthreads();
  int c0 = 0, c1 = 0, c2 = 0, c3 = 0;
  for (int i = threadIdx.x; i < NTOK / 4; i += 1024) {
    int4 v = b4[i];
    c0 += (v.x == 1) + (v.y == 1) + (v.z == 1) + (v.w == 1);
    c1 += (v.x == 2) + (v.y == 2) + (v.z == 2) + (v.w == 2);
    c2 += (v.x == 3) + (v.y == 3) + (v.z == 3) + (v.w == 3);
    c3 += (v.x == 4) + (v.y == 4) + (v.z == 4) + (v.w == 4);
  }
  if (c0) atomicAdd(&cnt[0], c0);
  if (c1) atomicAdd(&cnt[1], c1);
  if (c2) atomicAdd(&cnt[2], c2);
  if (c3) atomicAdd(&cnt[3], c3);
  __syncthreads();
  if (threadIdx.x == 0) {
    int off = 0, b1 = 0, b2 = 0;
    for (int g = 0; g < 4; ++g) {
      int c = cnt[g];
      hdr[g] = c;
      hdr[8 + g] = off;
      hdr[4 + g] = off;   // cursor
      hdr[13 + g] = b1;
      hdr[18 + g] = b2;
      int mt = (c + 127) >> 7;   // 128-row m-tiles
      off += c;
      b1 += mt * 16;
      b2 += mt * 4;
    }
    hdr[12] = off; hdr[17] = b1; hdr[22] = b2;
  }
}

// LDS-aggregated fill: one global atomic per (block, expert).
__global__ void k_fill(const int* __restrict__ b_seq, int* __restrict__ hdr,
                       int* __restrict__ perm) {
  __shared__ int lcnt[4], base[4];
  const int tid = threadIdx.x;
  if (tid < 4) lcnt[tid] = 0;
  __syncthreads();
  const int i = blockIdx.x * 256 + tid;
  const int g = b_seq[i];
  int r = -1;
  if (g > 0) r = atomicAdd(&lcnt[g - 1], 1);
  __syncthreads();
  if (tid < 4) {
    int c = lcnt[tid];
    base[tid] = c ? atomicAdd(&hdr[4 + tid], c) : 0;
  }
  __syncthreads();
  if (g > 0) perm[base[g - 1] + r] = i;
}

// Gather + convert x into packed A tiles: xa[mtile][ks(8)][128][64].
// One block per (mtile, ks): 8x the parallelism of the r11-r14 version.
// Thread t: row = t>>1, half-chunk = t&1 (32 floats -> 32 bf16 = 64B).
// OOB rows of partial tiles are zero-filled.
__global__ __launch_bounds__(256)
void k_pack_a(const float* __restrict__ x, const int* __restrict__ hdr,
              const int* __restrict__ perm, __hip_bfloat16* __restrict__ xa) {
  const int nmt = hdr[17] >> 4;
  const int b = blockIdx.x >> 3, ks = blockIdx.x & 7;
  if (b >= nmt) return;
  int g = 0;
  while ((hdr[13 + g + 1] >> 4) <= b) ++g;
  const int mt = b - (hdr[13 + g] >> 4);
  const int off = hdr[8 + g], cnt = hdr[g];
  int nrows = cnt - (mt << 7);
  nrows = nrows > 128 ? 128 : nrows;
  const int t = threadIdx.x, r = t >> 1, h = t & 1;
  __hip_bfloat16* dst =
      xa + ((size_t)b << 16) + (ks << 13) + r * 64 + h * 32;
  if (r < nrows) {
    const float* src = x + (size_t)perm[off + (mt << 7) + r] * HDIM +
                       (ks << 6) + (h << 5);
    union { __hip_bfloat16 b16[32]; s16x8 v[4]; } u;
#pragma unroll
    for (int p = 0; p < 8; ++p) {
      float4 vv = *(const float4*)(src + p * 4);
      u.b16[p * 4 + 0] = __float2bfloat16(vv.x);
      u.b16[p * 4 + 1] = __float2bfloat16(vv.y);
      u.b16[p * 4 + 2] = __float2bfloat16(vv.z);
      u.b16[p * 4 + 3] = __float2bfloat16(vv.w);
    }
    s16x8* d = (s16x8*)dst;
#pragma unroll
    for (int p = 0; p < 4; ++p) d[p] = u.v[p];
  } else {
    const s16x8 zz = {0, 0, 0, 0, 0, 0, 0, 0};
    s16x8* d = (s16x8*)dst;
#pragma unroll
    for (int p = 0; p < 4; ++p) d[p] = zz;
  }
}

// Transpose+convert W into PACKED K-step tiles:
//   dst tile = (g*(C/128) + (rI/128))*(R/64) + kI/64, elem [rI&127][kI&63]
// grid (C/64, R/64, NEXP), block 256. Stores fully coalesced.
__global__ void k_transpose_cvt(const float* __restrict__ src,
                                __hip_bfloat16* __restrict__ dst, int R, int C) {
  __shared__ float tile[64][69];   // pad 69: conflict-free col reads
  const int g = blockIdx.z;
  const float* S = src + (size_t)g * R * C;
  const int c0 = blockIdx.x << 6, r0 = blockIdx.y << 6;
  const int t = threadIdx.x;
  const int lr = t >> 4, lc = (t & 15) << 2;
#pragma unroll
  for (int p = 0; p < 4; ++p) {
    float4 v = *(const float4*)(S + (size_t)(r0 + lr + p * 16) * C + c0 + lc);
    float* tr = &tile[lr + p * 16][lc];
    tr[0] = v.x; tr[1] = v.y; tr[2] = v.z; tr[3] = v.w;
  }
  __syncthreads();
  const int c = t >> 2, rq = t & 3;
  union { __hip_bfloat16 b[8]; s16x8 v; } u0, u1;
#pragma unroll
  for (int j = 0; j < 8; ++j) {
    u0.b[j] = __float2bfloat16(tile[rq * 16 + j][c]);
    u1.b[j] = __float2bfloat16(tile[rq * 16 + 8 + j][c]);
  }
  const int rI = c0 + c, kI = r0 + rq * 16;
  const size_t idx =
      ((size_t)((g * (C >> 7) + (rI >> 7)) * (R >> 6) + (kI >> 6)) << 13) +
      ((rI & 127) << 6) + (kI & 63);
  *(s16x8*)(dst + idx) = u0.v;
  *(s16x8*)(dst + idx + 8) = u1.v;
}

__device__ __forceinline__ f32x4 mfma16(s16x8 a, s16x8 b, f32x4 c) {
  asm("v_mfma_f32_16x16x32_bf16 %0, %1, %2, %0" : "+v"(c) : "v"(a), "v"(b));
  return c;
}

__device__ __forceinline__ void gload16(const void* g, void* lds) {
  __builtin_amdgcn_global_load_lds(
      (const __attribute__((address_space(1))) unsigned int*)g,
      (__attribute__((address_space(3))) unsigned int*)lds, 16, 0, 0);
}

// Grouped GEMM, 128x128 tile, BK=64, 4 waves each computing [64,64].
// Operands packed [tile][ks][128][64]; contiguous-1KB staging; XOR swizzle
// within blocks; fragment reads kb ^ ((row&7)<<4) (r7-r14 proven).
// K-loop (T4): STAGE(0,0); for s: { STAGE(s+1,p^1); vmcnt(8); barrier;
//   setprio(1); COMPUTE(p); setprio(0); barrier; }   [T5 added this round]
// MODE 1: A = xa (K=512), B = W1p; relu+bias; C staged in LDS (stride 272)
//         then 128B stores into Hp in GEMM2's packed-tile layout.
// MODE 2: A = Hp (K=2048), B = W2p; +bias; fp32 scatter to d_out via perm.
template <int MODE>
__global__ __launch_bounds__(256, 2)
void k_gemm(const int* __restrict__ hdr, const int* __restrict__ perm,
            const __hip_bfloat16* __restrict__ Ap,
            const __hip_bfloat16* __restrict__ Bp,
            const float* __restrict__ bias,
            __hip_bfloat16* __restrict__ Hout, float* __restrict__ Yout) {
  constexpr int NS   = (MODE == 1) ? 8 : 32;   // K-steps
  constexpr int NT   = (MODE == 1) ? 16 : 4;   // n-tiles
  constexpr int NF   = (MODE == 1) ? FDIM : HDIM;
  const int* tb = hdr + ((MODE == 1) ? 13 : 18);
  const int total = tb[4];

  __shared__ __align__(16) char LDS[65536];
  char* As = LDS;            // + p*16384
  char* Bs = LDS + 32768;    // + p*16384

  const int idx = blockIdx.x;
  if (idx >= total) return;
  // m204 runtime-bijective XCD swizzle on the actual tile count
  const int qc = total >> 3, rc = total & 7;
  const int xcd = idx & 7;
  const int cbase = (xcd < rc) ? xcd * (qc + 1) : rc * (qc + 1) + (xcd - rc) * qc;
  const int w = cbase + (idx >> 3);

  const int tid = threadIdx.x, lane = tid & 63, wv = tid >> 6;
  const int wm = (wv >> 1) << 6, wn = (wv & 1) << 6;
  const int l15 = lane & 15, lq = lane >> 4;
  const int rsub = lane >> 3, c8 = lane & 7;      // staging: row-sub, chunk

  int g = 0;
  while (tb[g + 1] <= w) ++g;
  const int local = w - tb[g];
  const int mt = local / NT, nt = local % NT;
  const int cnt = hdr[g], off = hdr[8 + g];
  int nrows = cnt - (mt << 7);
  nrows = nrows > 128 ? 128 : nrows;

  // packed-tile sequence bases; K-step s adds s*8192 elements
  const int amt = (MODE == 1) ? (hdr[13 + g] >> 4) + mt
                              : (hdr[18 + g] >> 2) + mt;
  const int lelem = ((wv << 5) + rsub) * 64 + ((c8 ^ rsub) << 3);
  const __hip_bfloat16* abase = Ap + (((size_t)amt * NS) << 13) + lelem;
  const __hip_bfloat16* bbase =
      Bp + (((size_t)(g * NT + nt) * NS) << 13) + lelem;

  f32x4 acc[4][4];
  const f32x4 fz = {0.f, 0.f, 0.f, 0.f};
#pragma unroll
  for (int m = 0; m < 4; ++m)
#pragma unroll
    for (int n = 0; n < 4; ++n) acc[m][n] = fz;

  auto STAGE = [&](int s, int p) {
    const size_t so = (size_t)s << 13;
    char* Ad = As + (p << 14) + (wv << 12);
    char* Bd = Bs + (p << 14) + (wv << 12);
#pragma unroll
    for (int i = 0; i < 4; ++i) {
      gload16(abase + so + (i << 9), Ad + (i << 10));
      gload16(bbase + so + (i << 9), Bd + (i << 10));
    }
  };
  auto COMPUTE = [&](int p) {
    const char* Ab = As + (p << 14);
    const char* Bb = Bs + (p << 14);
#pragma unroll
    for (int kk = 0; kk < 2; ++kk) {
      const int kb = (kk << 6) + (lq << 4);
      s16x8 a[4], b[4];
#pragma unroll
      for (int m = 0; m < 4; ++m) {
        const int row = wm + (m << 4) + l15;
        a[m] = *(const s16x8*)(Ab + (row << 7) + (kb ^ ((row & 7) << 4)));
      }
#pragma unroll
      for (int n = 0; n < 4; ++n) {
        const int row = wn + (n << 4) + l15;
        b[n] = *(const s16x8*)(Bb + (row << 7) + (kb ^ ((row & 7) << 4)));
      }
      __builtin_amdgcn_s_setprio(1);           // T5: favor MFMA wave
#pragma unroll
      for (int m = 0; m < 4; ++m)
#pragma unroll
        for (int n = 0; n < 4; ++n)
          acc[m][n] = mfma16(a[m], b[n], acc[m][n]);
      __builtin_amdgcn_s_setprio(0);
    }
  };

  // counted depth-2 pipeline (T4)
  STAGE(0, 0);
  for (int s = 0; s < NS; ++s) {
    const int p = s & 1;
    if (s + 1 < NS) {
      STAGE(s + 1, p ^ 1);
      asm volatile("s_waitcnt vmcnt(8)" ::: "memory");  // step-s retired
    } else {
      asm volatile("s_waitcnt vmcnt(0)" ::: "memory");
    }
    __builtin_amdgcn_s_barrier();              // step-s data visible to all
    asm volatile("" ::: "memory");
    COMPUTE(p);
    asm volatile("" ::: "memory");
    __builtin_amdgcn_s_barrier();              // reads of p done before
    asm volatile("" ::: "memory");             // next STAGE overwrites p
  }
  asm volatile("s_nop 7\ns_nop 7\ns_nop 7");   // MFMA->VALU hazard guard

  const int rq = lq << 2;
  if constexpr (MODE == 1) {
    // stage relu(acc+bias) in LDS (stride 272), then 128B stores into Hp's
    // packed layout: tile (amt2*32 + nt*2 + hf), elem [r][f&63].
#pragma unroll
    for (int n = 0; n < 4; ++n) {
      const int col = wn + (n << 4) + l15;
      const float bv = bias[g * NF + (nt << 7) + col];
#pragma unroll
      for (int m = 0; m < 4; ++m)
#pragma unroll
        for (int j = 0; j < 4; ++j) {
          const int row = wm + (m << 4) + rq + j;
          float v = acc[m][n][j] + bv;
          v = v > 0.f ? v : 0.f;
          *(__hip_bfloat16*)(LDS + row * 272 + col * 2) = __float2bfloat16(v);
        }
    }
    __syncthreads();
    const int r = tid >> 1, hf = tid & 1;
    if (r < nrows) {
      const char* src = LDS + r * 272 + hf * 128;
      const size_t tIdx =
          ((size_t)((hdr[18 + g] >> 2) + mt) * 32 + (nt << 1) + hf);
      char* dst = (char*)(Hout + (tIdx << 13) + r * 64);
#pragma unroll
      for (int q = 0; q < 8; ++q)
        *(s16x8*)(dst + q * 16) = *(const s16x8*)(src + q * 16);
    }
  } else {
#pragma unroll
    for (int n = 0; n < 4; ++n) {
      const int ncol = (nt << 7) + wn + (n << 4) + l15;
      const float bv = bias[g * NF + ncol];
#pragma unroll
      for (int m = 0; m < 4; ++m)
#pragma unroll
        for (int j = 0; j < 4; ++j) {
          const int rl = wm + (m << 4) + rq + j;
          if (rl < nrows) {
            const int tok = perm[off + (mt << 7) + rl];
            Yout[((size_t)tok << 9) + ncol] = acc[m][n][j] + bv;
          }
        }
    }
  }
}

extern "C" void kernel_launch(void* const* d_in, const int* in_sizes, int n_in,
                              void* d_out, int out_size, void* d_ws,
                              size_t ws_size, hipStream_t stream) {
  const float* x    = (const float*)d_in[0];
  const int* b_seq  = (const int*)d_in[1];
  const float* W1   = (const float*)d_in[2];
  const float* B1   = (const float*)d_in[3];
  const float* W2   = (const float*)d_in[4];
  const float* B2   = (const float*)d_in[5];
  float* out        = (float*)d_out;

  char* ws = (char*)d_ws;
  int* hdr  = (int*)ws;                          // 1 KB header
  int* perm = (int*)(ws + 1024);                 // 64 KB
  __hip_bfloat16* xa  = (__hip_bfloat16*)(ws + 66560);   // 132 mtiles
  __hip_bfloat16* W1p = xa + (size_t)MAXMT * 8 * 8192;   // [4*16][8] tiles
  __hip_bfloat16* W2p = W1p + (size_t)NEXP * FDIM * HDIM;// [4*4][32] tiles
  __hip_bfloat16* Hp  = W2p + (size_t)NEXP * HDIM * FDIM;// 132*32 tiles

  const int n4 = NTOK * HDIM / 4;

  k_init<<<2048, 256, 0, stream>>>(b_seq, (float4*)out, n4);
  k_count_scan<<<1, 1024, 0, stream>>>((const int4*)b_seq, hdr);
  k_fill<<<NTOK / 256, 256, 0, stream>>>(b_seq, hdr, perm);
  k_pack_a<<<MAXMT * 8, 256, 0, stream>>>(x, hdr, perm, xa);
  k_transpose_cvt<<<dim3(FDIM / 64, HDIM / 64, NEXP), 256, 0, stream>>>(
      W1, W1p, HDIM, FDIM);
  k_transpose_cvt<<<dim3(HDIM / 64, FDIM / 64, NEXP), 256, 0, stream>>>(
      W2, W2p, FDIM, HDIM);
  // grids cover worst-case tile counts; blocks past the actual total exit
  k_gemm<1><<<2112, 256, 0, stream>>>(hdr, perm, xa, W1p, B1, Hp, nullptr);
  k_gemm<2><<<528, 256, 0, stream>>>(hdr, perm, Hp, W2p, B2, nullptr, out);
}